// Round 9
// baseline (391.561 us; speedup 1.0000x reference)
//
#include <hip/hip_runtime.h>
#include <hip/hip_bf16.h>
#include <hip/hip_cooperative_groups.h>
#include <stdint.h>

namespace cg = cooperative_groups;

// Problem constants (fixed by the reference).
constexpr int N_SAE  = 128;
constexpr int D_DATA = 128;
constexpr int D_DICT = 512;
constexpr int B_TOK  = 1024;

constexpr int NCHUNK = 8;                // dict-dim chunks per expert (weights read once)
constexpr int CW     = D_DICT / NCHUNK;  // 64 dict cols per block
constexpr int NT     = 256;              // 4 waves
constexpr int TILE   = 16;               // tokens per MFMA tile (M=16)
constexpr int CAP    = 64;               // max tokens per expert (mean 16)
constexpr int APITCH = 66;               // s_acts row pitch in floats

typedef __attribute__((ext_vector_type(8))) short short8;   // 8 x bf16 (4 VGPRs)
typedef __attribute__((ext_vector_type(4))) int   int4v;    // same 4 VGPRs as 4x(2xbf16)
typedef __attribute__((ext_vector_type(4))) float f32x4;

// Packed f32x2 -> bf16x2 (RNE); lowers to v_cvt_pk_bf16_f32 where available.
__device__ __forceinline__ int cvt2i(float a, float b) {
    __hip_bfloat162 h = __float22bfloat162_rn(make_float2(a, b));
    union { __hip_bfloat162 v; int i; } u; u.v = h;
    return u.i;
}

__device__ __forceinline__ short f2bf(float f) {
    union { float f; uint32_t u; } v; v.f = f;
    uint32_t u = v.u;
    u += 0x7fffu + ((u >> 16) & 1u);     // round-to-nearest-even
    return (short)(u >> 16);
}

// ============================ FUSED (cooperative) ============================
__global__ __launch_bounds__(NT, 4)
void fused_kernel(const float* __restrict__ x,
                  const float* __restrict__ gate,
                  const float* __restrict__ W_enc,
                  const float* __restrict__ W_dec,
                  const float* __restrict__ b_enc,
                  const float* __restrict__ b_dec,
                  float* __restrict__ out,
                  float* __restrict__ P,        // [B_TOK][2][NCHUNK][D_DATA]
                  int* __restrict__ counts,
                  int* __restrict__ toks,       // packed tok | j<<12
                  float* __restrict__ gvs)
{
    cg::grid_group gg = cg::this_grid();
    const int bid  = blockIdx.x;     // 1024 blocks
    const int tid  = threadIdx.x;
    const int lane = tid & 63;

    __shared__ float s_acts[TILE * APITCH];  // ~4.2 KB (reused as reduce scratch)
    __shared__ int   s_tok[CAP];
    __shared__ float s_g[CAP];
    __shared__ int   s_half;

    // ---- Phase A: zero expert counters (poisoned each launch) ----
    if (bid == 0 && tid < N_SAE) counts[tid] = 0;
    gg.sync();

    // ---- Phase B: route token row t = bid (ballot rank for j) ----
    {
        float g = 0.f;
        if (tid < 128) g = gate[(size_t)bid * N_SAE + tid];
        unsigned long long m = __ballot(g != 0.0f);            // waves 2,3: m==0
        int jpart = __popcll(m & ((1ull << lane) - 1ull));
        if (tid == 0) s_half = __popcll(m);                    // nonzeros in e 0..63
        __syncthreads();
        if (tid < 128 && g != 0.0f) {
            int j    = jpart + (tid >= 64 ? s_half : 0);       // rank within row (0/1)
            int slot = atomicAdd(&counts[tid], 1);
            if (slot < CAP) {
                toks[tid * CAP + slot] = bid | (j << 12);
                gvs[tid * CAP + slot]  = g;
            }
        }
    }

    // ---- Weight fragments (independent of routing; loads drain over sync) ----
    const int e  = bid >> 3;         // expert
    const int c  = bid & 7;          // dict chunk
    const int w  = tid >> 6;         // wave id = encode col-tile
    const int lo = lane & 15;        // MFMA m/n index
    const int q  = lane >> 4;        // MFMA quad (k group)

    int4v iWe[4];
    {
        const float* We = W_enc + (size_t)e * D_DATA * D_DICT
                        + (size_t)c * CW + w * 16 + lo;
        #pragma unroll
        for (int kb = 0; kb < 4; ++kb) {
            #pragma unroll
            for (int j = 0; j < 8; j += 2) {
                int d = kb * 32 + q * 8 + j;
                iWe[kb][j >> 1] = cvt2i(We[(size_t)d * D_DICT],
                                        We[(size_t)(d + 1) * D_DICT]);
            }
        }
    }
    int4v iWd[2][2];
    {
        #pragma unroll
        for (int s = 0; s < 2; ++s) {
            const float* Wd = W_dec + ((size_t)e * D_DICT + c * CW) * D_DATA
                            + (2 * w + s) * 16 + lo;
            #pragma unroll
            for (int kb = 0; kb < 2; ++kb) {
                #pragma unroll
                for (int j = 0; j < 8; j += 2) {
                    int er = kb * 32 + q * 8 + j;
                    iWd[s][kb][j >> 1] = cvt2i(Wd[(size_t)er * D_DATA],
                                               Wd[(size_t)(er + 1) * D_DATA]);
                }
            }
        }
    }
    const float be = b_enc[(size_t)e * D_DICT + c * CW + w * 16 + lo];
    float bdv[2] = {0.f, 0.f};
    if (c == 0) {
        bdv[0] = b_dec[(size_t)e * D_DATA + (2 * w + 0) * 16 + lo];
        bdv[1] = b_dec[(size_t)e * D_DATA + (2 * w + 1) * 16 + lo];
    }

    gg.sync();   // routing lists globally visible

    // ---- Phase C: encode + decode for (expert e, chunk c) ----
    const int n = min(counts[e], CAP);
    if (tid < CAP) {
        s_tok[tid] = (tid < n) ? toks[e * CAP + tid] : 0;
        s_g[tid]   = (tid < n) ? gvs[e * CAP + tid]  : 0.f;
    }
    __syncthreads();

    for (int t0 = 0; t0 < n; t0 += TILE) {
        // x A-fragments: lane m = lo -> token slot t0+lo (clamped)
        int4v ix[4];
        {
            int slot = t0 + lo;
            if (slot >= n) slot = n - 1;
            const float* xr = x + (size_t)(s_tok[slot] & 4095) * D_DATA;
            #pragma unroll
            for (int kb = 0; kb < 4; ++kb) {
                #pragma unroll
                for (int j = 0; j < 8; j += 2) {
                    float2 v = *(const float2*)&xr[kb * 32 + q * 8 + j];
                    ix[kb][j >> 1] = cvt2i(v.x, v.y);
                }
            }
        }

        // encode: acts[16 tok x 16 cols] per wave, K = 128
        f32x4 acc = {be, be, be, be};
        #pragma unroll
        for (int kb = 0; kb < 4; ++kb)
            acc = __builtin_amdgcn_mfma_f32_16x16x32_bf16(
                __builtin_bit_cast(short8, ix[kb]),
                __builtin_bit_cast(short8, iWe[kb]), acc, 0, 0, 0);

        #pragma unroll
        for (int r = 0; r < 4; ++r) {
            int row = q * 4 + r;
            float g = s_g[t0 + row];
            s_acts[row * APITCH + w * 16 + lo] = fmaxf(acc[r], 0.f) * g;
        }
        __syncthreads();

        // decode A-fragments from s_acts: m = lo (token), k = dict-local
        int4v ia[2];
        #pragma unroll
        for (int kb = 0; kb < 2; ++kb) {
            #pragma unroll
            for (int j = 0; j < 8; j += 2) {
                float2 v = *(const float2*)&s_acts[lo * APITCH + kb * 32 + q * 8 + j];
                ia[kb][j >> 1] = cvt2i(v.x, v.y);
            }
        }

        #pragma unroll
        for (int s = 0; s < 2; ++s) {
            f32x4 oc = {bdv[s], bdv[s], bdv[s], bdv[s]};
            #pragma unroll
            for (int kb = 0; kb < 2; ++kb)
                oc = __builtin_amdgcn_mfma_f32_16x16x32_bf16(
                    __builtin_bit_cast(short8, ia[kb]),
                    __builtin_bit_cast(short8, iWd[s][kb]), oc, 0, 0, 0);
            #pragma unroll
            for (int r = 0; r < 4; ++r) {
                int row = q * 4 + r;
                int slot = t0 + row;
                if (slot < n) {
                    int v   = s_tok[slot];
                    int tok = v & 4095, jj = v >> 12;
                    P[(((size_t)tok * 2 + jj) * NCHUNK + c) * D_DATA
                      + (2 * w + s) * 16 + lo] = oc[r];
                }
            }
        }
        __syncthreads();
    }

    gg.sync();   // all partials visible

    // ---- Phase D: reduce token t = bid (16 contiguous partial rows) ----
    {
        const int col = tid & 127, h = tid >> 7;
        const float* p = P + (size_t)bid * 2 * NCHUNK * D_DATA + col;
        float s = 0.f;
        #pragma unroll
        for (int i = 0; i < NCHUNK; ++i) s += p[(size_t)(h * NCHUNK + i) * D_DATA];
        s_acts[tid] = s;
        __syncthreads();
        if (h == 0) out[(size_t)bid * D_DATA + col] = s_acts[col] + s_acts[128 + col];
    }
}

// ===================== Fallback: proven R7 3-kernel path =====================
__global__ __launch_bounds__(NT)
void route_kernel(const float* __restrict__ gate,
                  int* __restrict__ counts,
                  int* __restrict__ toks,
                  float* __restrict__ gvs)
{
    __shared__ int s_half[2];
    const int row  = threadIdx.x >> 7;
    const int t    = blockIdx.x * 2 + row;
    const int e    = threadIdx.x & 127;
    const int lane = threadIdx.x & 63;
    const int hi   = (threadIdx.x >> 6) & 1;

    float g = gate[(size_t)t * N_SAE + e];
    unsigned long long m = __ballot(g != 0.0f);
    int jpart = __popcll(m & ((1ull << lane) - 1ull));
    if (hi == 0 && lane == 0) s_half[row] = __popcll(m);
    __syncthreads();
    int j = jpart + (hi ? s_half[row] : 0);

    if (g != 0.0f) {
        int slot = atomicAdd(&counts[e], 1);
        if (slot < CAP) {
            toks[e * CAP + slot] = t | (j << 12);
            gvs[e * CAP + slot]  = g;
        }
    }
}

__global__ __launch_bounds__(NT, 4)
void moe_sae_kernel(const float* __restrict__ x,
                    const float* __restrict__ gate,
                    const float* __restrict__ W_enc,
                    const float* __restrict__ W_dec,
                    const float* __restrict__ b_enc,
                    const float* __restrict__ b_dec,
                    float* __restrict__ out,
                    float* __restrict__ P,
                    const int* __restrict__ counts,
                    const int* __restrict__ toks,
                    const float* __restrict__ gvs,
                    int use_part)
{
    const int e    = blockIdx.x;
    const int c    = blockIdx.y;
    const int tid  = threadIdx.x;
    const int lane = tid & 63;
    const int w    = tid >> 6;
    const int lo   = lane & 15;
    const int q    = lane >> 4;

    __shared__ float s_acts[TILE * APITCH];
    __shared__ int   s_tok[CAP];
    __shared__ float s_g[CAP];
    __shared__ int   s_count;

    short8 fWe[4];
    {
        const float* We = W_enc + (size_t)e * D_DATA * D_DICT
                        + (size_t)c * CW + w * 16 + lo;
        #pragma unroll
        for (int kb = 0; kb < 4; ++kb)
            #pragma unroll
            for (int j = 0; j < 8; ++j) {
                int d = kb * 32 + q * 8 + j;
                fWe[kb][j] = f2bf(We[(size_t)d * D_DICT]);
            }
    }
    short8 fWd[2][2];
    {
        #pragma unroll
        for (int s = 0; s < 2; ++s) {
            const float* Wd = W_dec + ((size_t)e * D_DICT + c * CW) * D_DATA
                            + (2 * w + s) * 16 + lo;
            #pragma unroll
            for (int kb = 0; kb < 2; ++kb)
                #pragma unroll
                for (int j = 0; j < 8; ++j) {
                    int er = kb * 32 + q * 8 + j;
                    fWd[s][kb][j] = f2bf(Wd[(size_t)er * D_DATA]);
                }
        }
    }

    const float be = b_enc[(size_t)e * D_DICT + c * CW + w * 16 + lo];
    float bdv[2] = {0.f, 0.f};
    if (c == 0) {
        bdv[0] = b_dec[(size_t)e * D_DATA + (2 * w + 0) * 16 + lo];
        bdv[1] = b_dec[(size_t)e * D_DATA + (2 * w + 1) * 16 + lo];
    }

    int n;
    if (use_part) {
        n = min(counts[e], CAP);
        if (tid < CAP) {
            s_tok[tid] = (tid < n) ? toks[e * CAP + tid] : 0;
            s_g[tid]   = (tid < n) ? gvs[e * CAP + tid]  : 0.f;
        }
        __syncthreads();
    } else {
        if (tid == 0) s_count = 0;
        __syncthreads();
        for (int i = tid; i < B_TOK; i += NT) {
            float gv = gate[(size_t)i * N_SAE + e];
            if (gv != 0.0f) {
                int slot = atomicAdd(&s_count, 1);
                if (slot < CAP) { s_tok[slot] = i; s_g[slot] = gv; }
            }
        }
        __syncthreads();
        n = min(s_count, CAP);
        if (tid >= n && tid < CAP) { s_tok[tid] = 0; s_g[tid] = 0.f; }
        __syncthreads();
    }
    if (n == 0) return;

    for (int t0 = 0; t0 < n; t0 += TILE) {
        short8 fx[4];
        {
            int slot = t0 + lo;
            if (slot >= n) slot = n - 1;
            const float* xr = x + (size_t)(s_tok[slot] & 4095) * D_DATA;
            #pragma unroll
            for (int kb = 0; kb < 4; ++kb)
                #pragma unroll
                for (int j = 0; j < 8; j += 2) {
                    float2 v = *(const float2*)&xr[kb * 32 + q * 8 + j];
                    fx[kb][j]     = f2bf(v.x);
                    fx[kb][j + 1] = f2bf(v.y);
                }
        }

        f32x4 acc = {be, be, be, be};
        #pragma unroll
        for (int kb = 0; kb < 4; ++kb)
            acc = __builtin_amdgcn_mfma_f32_16x16x32_bf16(fx[kb], fWe[kb], acc, 0, 0, 0);

        #pragma unroll
        for (int r = 0; r < 4; ++r) {
            int row = q * 4 + r;
            float g = s_g[t0 + row];
            s_acts[row * APITCH + w * 16 + lo] = fmaxf(acc[r], 0.f) * g;
        }
        __syncthreads();

        short8 fa[2];
        #pragma unroll
        for (int kb = 0; kb < 2; ++kb)
            #pragma unroll
            for (int j = 0; j < 8; j += 2) {
                float2 v = *(const float2*)&s_acts[lo * APITCH + kb * 32 + q * 8 + j];
                fa[kb][j]     = f2bf(v.x);
                fa[kb][j + 1] = f2bf(v.y);
            }

        #pragma unroll
        for (int s = 0; s < 2; ++s) {
            f32x4 oc = {bdv[s], bdv[s], bdv[s], bdv[s]};
            #pragma unroll
            for (int kb = 0; kb < 2; ++kb)
                oc = __builtin_amdgcn_mfma_f32_16x16x32_bf16(fa[kb], fWd[s][kb], oc, 0, 0, 0);
            if (use_part) {
                #pragma unroll
                for (int r = 0; r < 4; ++r) {
                    int row = q * 4 + r;
                    int slot = t0 + row;
                    if (slot < n) {
                        int v   = s_tok[slot];
                        int tok = v & 4095, jj = v >> 12;
                        P[(((size_t)tok * 2 + jj) * NCHUNK + c) * D_DATA
                          + (2 * w + s) * 16 + lo] = oc[r];
                    }
                }
            } else {
                #pragma unroll
                for (int r = 0; r < 4; ++r) {
                    int row = q * 4 + r;
                    if (t0 + row < n)
                        atomicAdd(&out[(size_t)(s_tok[t0 + row] & 4095) * D_DATA
                                       + (2 * w + s) * 16 + lo], oc[r]);
                }
            }
        }
        __syncthreads();
    }
}

__global__ __launch_bounds__(NT)
void reduce_kernel(const float* __restrict__ P, float* __restrict__ out)
{
    const int t   = blockIdx.x * 2 + (threadIdx.x >> 7);
    const int col = threadIdx.x & 127;
    const float* p = P + (size_t)t * 2 * NCHUNK * D_DATA + col;
    float s = 0.f;
    #pragma unroll
    for (int i = 0; i < 2 * NCHUNK; ++i) s += p[(size_t)i * D_DATA];
    out[(size_t)t * D_DATA + col] = s;
}

extern "C" void kernel_launch(void* const* d_in, const int* in_sizes, int n_in,
                              void* d_out, int out_size, void* d_ws, size_t ws_size,
                              hipStream_t stream) {
    const float* x     = (const float*)d_in[0];
    const float* gate  = (const float*)d_in[1];
    const float* W_enc = (const float*)d_in[2];
    const float* W_dec = (const float*)d_in[3];
    const float* b_enc = (const float*)d_in[4];
    const float* b_dec = (const float*)d_in[5];
    float* out = (float*)d_out;

    // ws layout: counts[128] | toks[128*CAP] | gvs[128*CAP] | P[B_TOK*2*NCHUNK*D_DATA]
    int*   counts = (int*)d_ws;
    int*   toks   = counts + N_SAE;
    float* gvs    = (float*)(toks + (size_t)N_SAE * CAP);
    float* P      = gvs + (size_t)N_SAE * CAP;
    const size_t ws_needed = (size_t)(N_SAE + 2 * N_SAE * CAP) * 4
                           + (size_t)B_TOK * 2 * NCHUNK * D_DATA * 4;
    int use_part = (ws_size >= ws_needed) ? 1 : 0;

    if (use_part) {
        // Preferred: single cooperative kernel (memset+route+moe+reduce fused).
        void* args[] = {
            (void*)&x, (void*)&gate, (void*)&W_enc, (void*)&W_dec,
            (void*)&b_enc, (void*)&b_dec, (void*)&out, (void*)&P,
            (void*)&counts, (void*)&toks, (void*)&gvs
        };
        hipError_t err = hipLaunchCooperativeKernel(
            reinterpret_cast<const void*>(&fused_kernel),
            dim3(N_SAE * NCHUNK), dim3(NT), args, 0, stream);
        if (err == hipSuccess) return;
        // fall through to 3-kernel path on any failure
        hipMemsetAsync(counts, 0, N_SAE * sizeof(int), stream);
        route_kernel<<<B_TOK / 2, NT, 0, stream>>>(gate, counts, toks, gvs);
        dim3 grid(N_SAE, NCHUNK);
        moe_sae_kernel<<<grid, NT, 0, stream>>>(x, gate, W_enc, W_dec, b_enc, b_dec,
                                                out, P, counts, toks, gvs, 1);
        reduce_kernel<<<B_TOK / 2, NT, 0, stream>>>(P, out);
    } else {
        // last-resort: atomic accumulation straight into d_out
        hipMemsetAsync(d_out, 0, (size_t)out_size * sizeof(float), stream);
        dim3 grid(N_SAE, NCHUNK);
        moe_sae_kernel<<<grid, NT, 0, stream>>>(x, gate, W_enc, W_dec, b_enc, b_dec,
                                                out, P, counts, toks, gvs, 0);
    }
}

// Round 10
// 122.546 us; speedup vs baseline: 3.1952x; 3.1952x over previous
//
#include <hip/hip_runtime.h>
#include <hip/hip_bf16.h>
#include <stdint.h>

// Problem constants (fixed by the reference).
constexpr int N_SAE  = 128;
constexpr int D_DATA = 128;
constexpr int D_DICT = 512;
constexpr int B_TOK  = 1024;

constexpr int NCHUNK = 8;                // dict-dim chunks per expert (weights read once)
constexpr int CW     = D_DICT / NCHUNK;  // 64 dict cols per block
constexpr int NT     = 256;              // 4 waves
constexpr int TILE   = 16;               // tokens per MFMA tile (M=16)
constexpr int CAP    = 64;               // max tokens per expert (mean 16)
constexpr int APITCH = 66;               // s_acts row pitch in floats

typedef __attribute__((ext_vector_type(8))) short short8;   // 8 x bf16 (4 VGPRs)
typedef __attribute__((ext_vector_type(4))) int   int4v;    // 4 x (2xbf16) = same 4 VGPRs
typedef __attribute__((ext_vector_type(4))) float f32x4;

// Packed f32x2 -> bf16x2 (RNE); lowers to v_cvt_pk_bf16_f32 on gfx950.
__device__ __forceinline__ int cvt2i(float a, float b) {
    __hip_bfloat162 h = __float22bfloat162_rn(make_float2(a, b));
    union { __hip_bfloat162 v; int i; } u; u.v = h;
    return u.i;
}

// ---- Routing: coalesced gate scan -> per-expert token lists.
// j = rank of this expert within token row (0/1, exactly K=2 nonzeros/row),
// via wave ballot. Packed entry: tok | (j << 12).
__global__ __launch_bounds__(NT)
void route_kernel(const float* __restrict__ gate,
                  int* __restrict__ counts,   // [N_SAE]  (pre-zeroed)
                  int* __restrict__ toks,     // [N_SAE][CAP] packed tok|j<<12
                  float* __restrict__ gvs)    // [N_SAE][CAP]
{
    __shared__ int s_half[2];                 // nonzeros among experts 0..63, per row
    const int row  = threadIdx.x >> 7;        // 0,1: token row within block
    const int t    = blockIdx.x * 2 + row;
    const int e    = threadIdx.x & 127;
    const int lane = threadIdx.x & 63;
    const int hi   = (threadIdx.x >> 6) & 1;  // expert half (each wave = one half)

    float g = gate[(size_t)t * N_SAE + e];    // fully coalesced
    unsigned long long m = __ballot(g != 0.0f);
    int jpart = __popcll(m & ((1ull << lane) - 1ull));
    if (hi == 0 && lane == 0) s_half[row] = __popcll(m);
    __syncthreads();
    int j = jpart + (hi ? s_half[row] : 0);   // rank of nonzero within row

    if (g != 0.0f) {
        int slot = atomicAdd(&counts[e], 1);
        if (slot < CAP) {
            toks[e * CAP + slot] = t | (j << 12);
            gvs[e * CAP + slot]  = g;
        }
    }
}

__global__ __launch_bounds__(NT, 4)
void moe_sae_kernel(const float* __restrict__ x,
                    const float* __restrict__ gate,
                    const float* __restrict__ W_enc,
                    const float* __restrict__ W_dec,
                    const float* __restrict__ b_enc,
                    const float* __restrict__ b_dec,
                    float* __restrict__ out,
                    float* __restrict__ P,        // [B_TOK][2][NCHUNK][D_DATA]
                    const int* __restrict__ counts,
                    const int* __restrict__ toks,
                    const float* __restrict__ gvs,
                    int use_part)
{
    const int e    = blockIdx.x;     // expert
    const int c    = blockIdx.y;     // dict chunk (64 cols)
    const int tid  = threadIdx.x;
    const int lane = tid & 63;
    const int w    = tid >> 6;       // wave id = encode col-tile
    const int lo   = lane & 15;      // MFMA m/n index
    const int q    = lane >> 4;      // MFMA quad (k group)

    __shared__ float s_acts[TILE * APITCH];  // ~4.2 KB
    __shared__ int   s_tok[CAP];             // packed tok | j<<12
    __shared__ float s_g[CAP];
    __shared__ int   s_count;

    // ---- Encode B-fragments (We): global f32 -> packed bf16 VGPR, read once ----
    int4v iWe[4];
    {
        const float* We = W_enc + (size_t)e * D_DATA * D_DICT
                        + (size_t)c * CW + w * 16 + lo;
        #pragma unroll
        for (int kb = 0; kb < 4; ++kb) {
            #pragma unroll
            for (int j = 0; j < 8; j += 2) {
                int d = kb * 32 + q * 8 + j;
                iWe[kb][j >> 1] = cvt2i(We[(size_t)d * D_DICT],
                                        We[(size_t)(d + 1) * D_DICT]);
            }
        }
    }
    // ---- Decode B-fragments (Wd): wave w covers out col-tiles {2w, 2w+1} ----
    int4v iWd[2][2];
    {
        #pragma unroll
        for (int s = 0; s < 2; ++s) {
            const float* Wd = W_dec + ((size_t)e * D_DICT + c * CW) * D_DATA
                            + (2 * w + s) * 16 + lo;
            #pragma unroll
            for (int kb = 0; kb < 2; ++kb) {
                #pragma unroll
                for (int j = 0; j < 8; j += 2) {
                    int er = kb * 32 + q * 8 + j;
                    iWd[s][kb][j >> 1] = cvt2i(Wd[(size_t)er * D_DATA],
                                               Wd[(size_t)(er + 1) * D_DATA]);
                }
            }
        }
    }

    const float be = b_enc[(size_t)e * D_DICT + c * CW + w * 16 + lo];
    float bdv[2] = {0.f, 0.f};
    if (c == 0) {
        bdv[0] = b_dec[(size_t)e * D_DATA + (2 * w + 0) * 16 + lo];
        bdv[1] = b_dec[(size_t)e * D_DATA + (2 * w + 1) * 16 + lo];
    }

    // ---- Routing lists (zero-padded so garbage rows compute finite zeros) ----
    int n;
    if (use_part) {
        n = min(counts[e], CAP);
        if (tid < CAP) {
            s_tok[tid] = (tid < n) ? toks[e * CAP + tid] : 0;
            s_g[tid]   = (tid < n) ? gvs[e * CAP + tid]  : 0.f;
        }
        __syncthreads();
    } else {
        if (tid == 0) s_count = 0;
        __syncthreads();
        for (int i = tid; i < B_TOK; i += NT) {
            float gv = gate[(size_t)i * N_SAE + e];
            if (gv != 0.0f) {
                int slot = atomicAdd(&s_count, 1);
                if (slot < CAP) { s_tok[slot] = i; s_g[slot] = gv; }
            }
        }
        __syncthreads();
        n = min(s_count, CAP);
        if (tid >= n && tid < CAP) { s_tok[tid] = 0; s_g[tid] = 0.f; }
        __syncthreads();
    }
    if (n == 0) return;

    for (int t0 = 0; t0 < n; t0 += TILE) {
        // ---- x A-fragments: lane m = lo -> token slot t0+lo (clamped) ----
        int4v ix[4];
        {
            int slot = t0 + lo;
            if (slot >= n) slot = n - 1;
            const float* xr = x + (size_t)(s_tok[slot] & 4095) * D_DATA;
            #pragma unroll
            for (int kb = 0; kb < 4; ++kb) {
                #pragma unroll
                for (int j = 0; j < 8; j += 2) {
                    float2 v = *(const float2*)&xr[kb * 32 + q * 8 + j];
                    ix[kb][j >> 1] = cvt2i(v.x, v.y);
                }
            }
        }

        // ---- encode: acts[16 tok x 16 cols] per wave, K = 128 ----
        f32x4 acc = {be, be, be, be};
        #pragma unroll
        for (int kb = 0; kb < 4; ++kb)
            acc = __builtin_amdgcn_mfma_f32_16x16x32_bf16(
                __builtin_bit_cast(short8, ix[kb]),
                __builtin_bit_cast(short8, iWe[kb]), acc, 0, 0, 0);

        // C-layout: col = lo (+w*16), row = q*4 + r.  relu * g, store to LDS.
        #pragma unroll
        for (int r = 0; r < 4; ++r) {
            int row = q * 4 + r;
            float g = s_g[t0 + row];
            s_acts[row * APITCH + w * 16 + lo] = fmaxf(acc[r], 0.f) * g;
        }
        __syncthreads();

        // ---- decode A-fragments from s_acts: m = lo (token), k = dict-local ----
        int4v ia[2];
        #pragma unroll
        for (int kb = 0; kb < 2; ++kb) {
            #pragma unroll
            for (int j = 0; j < 8; j += 2) {
                float2 v = *(const float2*)&s_acts[lo * APITCH + kb * 32 + q * 8 + j];
                ia[kb][j >> 1] = cvt2i(v.x, v.y);
            }
        }

        // ---- decode: out[16 tok x 16 cols] per col-tile, K = 64 ----
        #pragma unroll
        for (int s = 0; s < 2; ++s) {
            f32x4 oc = {bdv[s], bdv[s], bdv[s], bdv[s]};
            #pragma unroll
            for (int kb = 0; kb < 2; ++kb)
                oc = __builtin_amdgcn_mfma_f32_16x16x32_bf16(
                    __builtin_bit_cast(short8, ia[kb]),
                    __builtin_bit_cast(short8, iWd[s][kb]), oc, 0, 0, 0);
            if (use_part) {
                #pragma unroll
                for (int r = 0; r < 4; ++r) {
                    int row = q * 4 + r;
                    int slot = t0 + row;
                    if (slot < n) {
                        int v   = s_tok[slot];
                        int tok = v & 4095, jj = v >> 12;
                        P[(((size_t)tok * 2 + jj) * NCHUNK + c) * D_DATA
                          + (2 * w + s) * 16 + lo] = oc[r];
                    }
                }
            } else {
                #pragma unroll
                for (int r = 0; r < 4; ++r) {
                    int row = q * 4 + r;
                    if (t0 + row < n)
                        atomicAdd(&out[(size_t)(s_tok[t0 + row] & 4095) * D_DATA
                                       + (2 * w + s) * 16 + lo], oc[r]);
                }
            }
        }
        __syncthreads();   // s_acts reused next tile
    }
}

// ---- Final reduce: token t's 16 partials are contiguous — no indirection ----
__global__ __launch_bounds__(NT)
void reduce_kernel(const float* __restrict__ P, float* __restrict__ out)
{
    const int t   = blockIdx.x * 2 + (threadIdx.x >> 7);
    const int col = threadIdx.x & 127;
    const float* p = P + (size_t)t * 2 * NCHUNK * D_DATA + col;
    float s = 0.f;
    #pragma unroll
    for (int i = 0; i < 2 * NCHUNK; ++i) s += p[(size_t)i * D_DATA];
    out[(size_t)t * D_DATA + col] = s;
}

extern "C" void kernel_launch(void* const* d_in, const int* in_sizes, int n_in,
                              void* d_out, int out_size, void* d_ws, size_t ws_size,
                              hipStream_t stream) {
    const float* x     = (const float*)d_in[0];
    const float* gate  = (const float*)d_in[1];
    const float* W_enc = (const float*)d_in[2];
    const float* W_dec = (const float*)d_in[3];
    const float* b_enc = (const float*)d_in[4];
    const float* b_dec = (const float*)d_in[5];
    float* out = (float*)d_out;

    // ws layout: counts[128] | toks[128*CAP] | gvs[128*CAP] | P[B_TOK*2*NCHUNK*D_DATA]
    int*   counts = (int*)d_ws;
    int*   toks   = counts + N_SAE;
    float* gvs    = (float*)(toks + (size_t)N_SAE * CAP);
    float* P      = gvs + (size_t)N_SAE * CAP;
    const size_t ws_needed = (size_t)(N_SAE + 2 * N_SAE * CAP) * 4
                           + (size_t)B_TOK * 2 * NCHUNK * D_DATA * 4;
    int use_part = (ws_size >= ws_needed) ? 1 : 0;

    if (use_part) {
        hipMemsetAsync(counts, 0, N_SAE * sizeof(int), stream);   // 512 B only
        route_kernel<<<B_TOK / 2, NT, 0, stream>>>(gate, counts, toks, gvs);
    } else {
        // fallback: atomic accumulation straight into d_out
        hipMemsetAsync(d_out, 0, (size_t)out_size * sizeof(float), stream);
    }

    dim3 grid(N_SAE, NCHUNK);
    moe_sae_kernel<<<grid, NT, 0, stream>>>(x, gate, W_enc, W_dec, b_enc, b_dec, out,
                                            P, counts, toks, gvs, use_part);

    if (use_part)
        reduce_kernel<<<B_TOK / 2, NT, 0, stream>>>(P, out);
}